// Round 12
// baseline (1120.988 us; speedup 1.0000x reference)
//
#include <hip/hip_runtime.h>
#include <hip/hip_bf16.h>

#define BB 32
#define WW 384
#define LL 512
#define ITERS 16
#define NPB (WW * LL)
#define LROWS 514            // 1 + 512 + 1 halo rows
#define RP (LROWS * 8)       // shorts per octet-plane (4112)

typedef __attribute__((ext_vector_type(8))) short bf16x8;
typedef __attribute__((ext_vector_type(4))) float f32x4;

__device__ __forceinline__ float b2f(short s) {
    unsigned u = ((unsigned)(unsigned short)s) << 16;
    float f;
    __builtin_memcpy(&f, &u, 4);
    return f;
}
__device__ __forceinline__ short f2b(float v) {
    __hip_bfloat16 h = __float2bfloat16(v);
    return *(short*)&h;
}

// async global->LDS, 16B per lane; LDS dest = wave-uniform base + lane*16.
__device__ __forceinline__ void gld16(const short* g, short* l) {
    __builtin_amdgcn_global_load_lds(
        (const __attribute__((address_space(1))) unsigned int*)g,
        (__attribute__((address_space(3))) unsigned int*)l, 16, 0, 0);
}

// ---------------------------------------------------------------- prep
// All one-time prep fused into ONE kernel (writes disjoint, no
// cross-reads): wsplit_op | wsplit_h1 | wsplit_h2 | wx | zero_part |
// init_rows | zero_out (out is now accumulated via atomics).
__global__ __launch_bounds__(256) void prep(
    const float* __restrict__ op_w, const float* __restrict__ h1_w,
    const float* __restrict__ h2_w, short* __restrict__ wOph,
    short* __restrict__ wH1, short* __restrict__ wH2, float* __restrict__ wx,
    short* itAh, short* itAl, short* itBh, short* itBl,
    short* a1A, short* a1B, float* part, float* outz) {
    int bid = blockIdx.x, tid = threadIdx.x;
    if (bid < 1728) {                      // op_w -> [3][48][384][8] bf16
        int i = bid * 256 + tid;           // 442368 = 1728*256 exact
        int e = i & 7, co = (i >> 3) % 384, oct = (i >> 3) / 384 % 48,
            tap = i / (8 * 384 * 48);
        wOph[i] = f2b(op_w[(co * 385 + oct * 8 + e) * 3 + tap]);
    } else if (bid < 3456) {               // h1_w -> [3][48][384][8]
        int i = (bid - 1728) * 256 + tid;
        int e = i & 7, co = (i >> 3) % 384, oct = (i >> 3) / 384 % 48,
            tap = i / (8 * 384 * 48);
        wH1[i] = f2b(h1_w[(co * 384 + oct * 8 + e) * 3 + tap]);
    } else if (bid < 4320) {               // h2_w -> [3][48][192][8]
        int i = (bid - 3456) * 256 + tid;  // 221184 = 864*256 exact
        int e = i & 7, co = (i >> 3) % 192, oct = (i >> 3) / 192 % 48,
            tap = i / (8 * 192 * 48);
        wH2[i] = f2b(h2_w[(co * 384 + oct * 8 + e) * 3 + tap]);
    } else if (bid < 4325) {               // wx[tap][co] fp32 x-channel
        int i = (bid - 4320) * 256 + tid;
        if (i < 3 * 384) {
            int co = i % 384, tap = i / 384;
            wx[tap * 384 + co] = op_w[(co * 385 + 384) * 3 + tap];
        }
    } else if (bid < 4330) {               // zero part
        int i = (bid - 4325) * 256 + tid;
        if (i < (ITERS + 1) * 64) part[i] = 0.f;
    } else if (bid < 4394) {               // zero halo rows (64 sub-bids)
        int rb = bid - 4330;
        int row = (rb & 1) ? (LROWS - 1) : 0;
        int b = rb >> 1;
        for (int i = tid; i < 48 * 8; i += 256) {
            size_t o = (size_t)b * 48 * RP + (size_t)(i >> 3) * RP +
                       row * 8 + (i & 7);
            itAh[o] = 0; itAl[o] = 0; itBh[o] = 0; itBl[o] = 0;
            a1A[o] = 0; a1B[o] = 0;
        }
    } else {                               // zero out (2048 sub-bids)
        int i = (bid - 4394) * 256 + tid;  // 524288 = 2048*256 exact
        outz[i] = 0.f;
    }
}

// it0 = relu(conv1d(x, proj_w)) -> octet-planar hi/lo (48 oct) + LN stats.
// bid swizzled so bid%8 == XCD key (2b + (l>>8)) & 7 (matches op readers).
__global__ __launch_bounds__(256) void proj_relu(const float* __restrict__ x,
                                                 const float* __restrict__ wp,
                                                 short* __restrict__ oh,
                                                 short* __restrict__ ol,
                                                 float* __restrict__ part) {
    int low3 = blockIdx.x & 7, r0 = blockIdx.x >> 3;   // r0 0..31
    int sl_lo = r0 & 3, chi = r0 >> 2;                 // chi 0..7
    int c3 = chi * 8 + low3;                           // 0..63
    int b = c3 >> 1, sl = ((c3 & 1) << 2) | sl_lo;
    int tid = threadIdx.x;
    __shared__ float ws[WW * 3];
    __shared__ float xs[66];
    for (int i = tid; i < WW * 3; i += 256) ws[i] = wp[i];
    int l0 = sl * 64;
    for (int i = tid; i < 66; i += 256) {
        int l = l0 + i - 1;
        xs[i] = (l >= 0 && l < LL) ? x[b * LL + l] : 0.f;
    }
    __syncthreads();
    size_t sb = (size_t)b * 48 * RP;
    float s = 0.f, sq = 0.f;
    for (int idx = tid; idx < 64 * WW; idx += 256) {
        int lo = idx / WW, co = idx % WW;
        float v = fmaxf(ws[co * 3] * xs[lo] + ws[co * 3 + 1] * xs[lo + 1] +
                            ws[co * 3 + 2] * xs[lo + 2], 0.f);
        size_t o = sb + (size_t)(co >> 3) * RP + (l0 + lo + 1) * 8 + (co & 7);
        __hip_bfloat16 h = __float2bfloat16(v);
        oh[o] = *(short*)&h;
        ol[o] = f2b(v - __bfloat162float(h));
        s += v; sq += v * v;
    }
    #pragma unroll
    for (int off = 32; off > 0; off >>= 1) {
        s += __shfl_down(s, off);
        sq += __shfl_down(sq, off);
    }
    __shared__ float sr[8];
    int w = tid >> 6;
    if ((tid & 63) == 0) { sr[w] = s; sr[4 + w] = sq; }
    __syncthreads();
    if (tid == 0) {
        atomicAdd(&part[b * 2], sr[0] + sr[1] + sr[2] + sr[3]);
        atomicAdd(&part[b * 2 + 1], sr[4] + sr[5] + sr[6] + sr[7]);
    }
}

// ------------------------------------------------- MFMA implicit-GEMM conv
// v13 = v8 (best, 953us) + h3 FUSED INTO h2 (MODE 2). 13 rounds confirm:
// fusedF dur == (FETCH+WRITE)/1.5-1.6 TB/s and neither scheduling (v7/v8),
// occupancy (v10/v12), nor hints (v11) move it -- only byte removal can.
// a2 was 13MB/dispatch (6.4 write by h2 + 6.4 read by h3). Now the h2
// block's accumulator IS the a2 tile: after the K-loop it is written bf16
// into the DEAD STAGING LDS (same bf16 precision h3 read from global ->
// identical values), the 2 halo rows (seq l0-1, l0+256) are VALU-computed
// from global a1 + wH2 (zero at sequence edges, matching the pre-zeroed
// halo), and each thread computes the partial 192->2 conv over this
// block's 64 ci, atomicAdd-ing into pre-zeroed out (3 co-blocks combine;
// fp32 order nondeterminism ~1ulp << 2.4e-3 margin). a2 buffers, the h3
// branch, and one pipeline stage are gone. op/h1 branches byte-identical
// to v8. Accumulation order (kc asc, tap asc) identical -> same numerics.

#define PIPE_BARRIER()                                                     \
    do {                                                                   \
        asm volatile("s_waitcnt vmcnt(8)" ::: "memory");                   \
        __builtin_amdgcn_sched_barrier(0);                                 \
        __builtin_amdgcn_s_barrier();                                      \
        __builtin_amdgcn_sched_barrier(0);                                 \
    } while (0)

#define MMAC(A, B, MT, NT)                                                 \
    acc[MT][NT] = __builtin_amdgcn_mfma_f32_16x16x32_bf16(A, B,            \
                                                          acc[MT][NT], 0, 0, 0);

// Stage spans [S0,S1) of group KG into buffer TB. Span s_ = 64 16B-units,
// handled by wave (s_ - S0) % 4; last span clamped (benign same-data
// overlap). LDS layout per buffer: [GOCT][TLROWS] 16B-units.
#define STAGE_R(KG, TB, S0, S1)                                            \
    do {                                                                   \
        short* sb_ = smem + (TB) * ASZ;                                    \
        _Pragma("unroll")                                                  \
        for (int r_ = 0; r_ < ((S1) - (S0) + 3) / 4; r_++) {               \
            int s_ = (S0) + r_ * 4 + wn;                                   \
            if (s_ < (S1)) {                                               \
                int u0_ = s_ * 64;                                         \
                if (u0_ > AU - 64) u0_ = AU - 64;                          \
                int u_ = u0_ + lane;                                       \
                int oc_ = u_ / TLROWS;                                     \
                int rw_ = u_ - oc_ * TLROWS;                               \
                gld16(inh + ibase + (size_t)((KG) * GOCT + oc_) * RP +     \
                          (size_t)(l0 + rw_) * 8,                          \
                      sb_ + u0_ * 8);                                      \
            }                                                              \
        }                                                                  \
    } while (0)

#define DECL_B(S) bf16x8 fb0##S, fb1##S, fb2##S, fb3##S;

// Prefetch B frags for (tap T, sub-chunk KC) into set S (global->VGPR).
#define LOADB(S, T, KC)                                                    \
    do {                                                                   \
        const short* bp_ = wh + ((((size_t)(T) * CHUNKS + (KC)) * 4 + q) * \
                                     COD + co0w + lane15) * 8;             \
        fb0##S = *(const bf16x8*)(bp_);                                    \
        fb1##S = *(const bf16x8*)(bp_ + 16 * 8);                           \
        fb2##S = *(const bf16x8*)(bp_ + 32 * 8);                           \
        fb3##S = *(const bf16x8*)(bp_ + 48 * 8);                           \
    } while (0)

// One tap-step: 4 ds_read_b128 (A, sub-chunk OG of the group) + 16 MFMA.
#define COMP_TAP(SB, OG, T, S)                                             \
    do {                                                                   \
        const short* As_ = (SB);                                           \
        int ar_ = ((OG) * 4 + q) * TLROWS + wl + lane15 + (T);             \
        bf16x8 fa0 = *(const bf16x8*)(As_ + ar_ * 8);                      \
        bf16x8 fa1 = *(const bf16x8*)(As_ + (ar_ + 16) * 8);               \
        bf16x8 fa2 = *(const bf16x8*)(As_ + (ar_ + 32) * 8);               \
        bf16x8 fa3 = *(const bf16x8*)(As_ + (ar_ + 48) * 8);               \
        MMAC(fa0, fb0##S, 0, 0) MMAC(fa0, fb1##S, 0, 1)                    \
        MMAC(fa0, fb2##S, 0, 2) MMAC(fa0, fb3##S, 0, 3)                    \
        MMAC(fa1, fb0##S, 1, 0) MMAC(fa1, fb1##S, 1, 1)                    \
        MMAC(fa1, fb2##S, 1, 2) MMAC(fa1, fb3##S, 1, 3)                    \
        MMAC(fa2, fb0##S, 2, 0) MMAC(fa2, fb1##S, 2, 1)                    \
        MMAC(fa2, fb2##S, 2, 2) MMAC(fa2, fb3##S, 2, 3)                    \
        MMAC(fa3, fb0##S, 3, 0) MMAC(fa3, fb1##S, 3, 1)                    \
        MMAC(fa3, fb2##S, 3, 2) MMAC(fa3, fb3##S, 3, 3)                    \
    } while (0)

template <int CHUNKS, int IOCT, int OOCT, int COD, int MODE, int LSPLIT,
          int GOCT>
__device__ __forceinline__ void conv_body(
    int bid, short* smem, float* ws3s,
    const short* __restrict__ inh, const short* __restrict__ inl,
    const short* __restrict__ wh, const float* __restrict__ xf,
    const float* __restrict__ wx, const float* __restrict__ part_in,
    float* __restrict__ part_out, short* __restrict__ outh,
    short* __restrict__ outl, const float* __restrict__ w3p,
    float* __restrict__ outp, int th) {
    constexpr int TLROWS = LSPLIT ? 258 : 130;  // staged halo rows per octet
    constexpr int SUBS = GOCT / 4;              // sub-chunks per group
    constexpr int NG = CHUNKS / SUBS;           // groups (= barriers)
    constexpr int ASZ = GOCT * TLROWS * 8;      // shorts per A buffer
    constexpr int AU = GOCT * TLROWS;           // A 16B-units per group
    constexpr int ANS = (AU + 63) / 64;         // spans per group
    constexpr int SPS = (ANS + SUBS - 1) / SUBS;  // spans per sub-chunk

    int tid = threadIdx.x;
    int lane = tid & 63;
    int wn = __builtin_amdgcn_readfirstlane(tid >> 6);
    int lane15 = lane & 15, q = lane >> 4;
    int b, l0, co0, wl, wco;
    if (LSPLIT) {
        // XCD-keyed decode: bid%8 == (2b + lt2) & 7, lt2 = l>>8.
        int low3 = bid & 7, r0 = bid >> 3;      // r0 0..23
        int ct = r0 % 3, chi = r0 / 3;          // chi 0..7
        int c2 = chi * 8 + low3;                // 0..63
        b = c2 >> 1; l0 = (c2 & 1) * 256; co0 = ct * 64;
        wl = wn * 64; wco = 0;
    } else {
        // XCD-keyed decode: bid%8 == (2b + (lt>>1)) & 7, lt = l>>7 (0..3).
        int low3 = bid & 7, r0 = bid >> 3;      // r0 0..47
        int ct = r0 % 3, s2 = r0 / 3;           // s2 0..15
        int ltlo = s2 & 1, chi = s2 >> 1;       // chi 0..7
        int c = chi * 8 + low3;                 // 0..63
        b = c >> 1;
        int lt = ((c & 1) << 1) | ltlo;         // 0..3
        l0 = lt * 128; co0 = ct * 128;
        wl = (wn >> 1) * 64; wco = (wn & 1) * 64;
    }
    const int co0w = co0 + wco;
    const size_t ibase = (size_t)b * IOCT * RP;

    f32x4 acc[4][4];
    #pragma unroll
    for (int i = 0; i < 4; i++)
        #pragma unroll
        for (int j = 0; j < 4; j++) acc[i][j] = (f32x4){0.f, 0.f, 0.f, 0.f};

    DECL_B(X)
    DECL_B(Y)
    DECL_B(Z)
    STAGE_R(0, 0, 0, ANS);
    LOADB(X, 0, 0);
    LOADB(Y, 1, 0);
    PIPE_BARRIER();    // vmcnt(8): STAGE(0) landed, X/Y stay in flight
    #pragma unroll 2
    for (int g = 0; g < NG; g++) {
        int cur = g & 1;
        short* sb = smem + cur * ASZ;
        #pragma unroll
        for (int s = 0; s < SUBS; s++) {
            int kc = g * SUBS + s;
            LOADB(Z, 2, kc);
            if (g + 1 < NG) {
                int s0 = s * SPS;
                int s1 = (s0 + SPS > ANS) ? ANS : s0 + SPS;
                STAGE_R(g + 1, cur ^ 1, s0, s1);
            }
            COMP_TAP(sb, s, 0, X);
            if (kc + 1 < CHUNKS) LOADB(X, 0, kc + 1);
            COMP_TAP(sb, s, 1, Y);
            if (kc + 1 < CHUNKS) LOADB(Y, 1, kc + 1);
            COMP_TAP(sb, s, 2, Z);
        }
        PIPE_BARRIER();  // vmcnt(8): STAGE(g+1) landed; X/Y cross over
    }

    int l0w = l0 + wl;
    const size_t obase = (size_t)b * OOCT * RP;
    if constexpr (MODE == 1) {
        float s_in = part_in[b * 2], sq_in = part_in[b * 2 + 1];
        float mu = s_in / (float)NPB;
        float var = sq_in / (float)NPB - mu * mu;
        float rs = rsqrtf(var + 1e-5f);
        const float* xb = xf + b * LL;
        float s = 0.f, sq = 0.f;
        #pragma unroll
        for (int nt = 0; nt < 4; nt++) {
            int n = co0w + nt * 16 + lane15;
            float w0 = wx[n], w1 = wx[384 + n], w2 = wx[768 + n];
            #pragma unroll
            for (int mt = 0; mt < 4; mt++)
                #pragma unroll
                for (int r = 0; r < 4; r++) {
                    int m = mt * 16 + q * 4 + r;
                    int l = l0w + m;
                    size_t idx = ibase + (size_t)(n >> 3) * RP +
                                 (l + 1) * 8 + (n & 7);
                    // x-channel contribution (fp32-exact)
                    float xm1 = (l > 0) ? xb[l - 1] : 0.f;
                    float xp1 = (l < LL - 1) ? xb[l + 1] : 0.f;
                    float c = acc[mt][nt][r] + w0 * xm1 + w1 * xb[l] + w2 * xp1;
                    float itv = b2f(inh[idx]) + b2f(inl[idx]);
                    float xl = (itv - mu) * rs;
                    float nv = xl - 0.1f * c - 0.2f * fmaxf(xl, 0.f);
                    s += nv;
                    sq += nv * nv;
                    __hip_bfloat16 h = __float2bfloat16(nv);
                    outh[idx] = *(short*)&h;
                    outl[idx] = f2b(nv - __bfloat162float(h));
                }
        }
        #pragma unroll
        for (int off = 32; off > 0; off >>= 1) {
            s += __shfl_down(s, off);
            sq += __shfl_down(sq, off);
        }
        __shared__ float sr[8];
        if (lane == 0) { sr[wn] = s; sr[4 + wn] = sq; }
        __syncthreads();
        if (tid == 0) {
            atomicAdd(&part_out[b * 2], sr[0] + sr[1] + sr[2] + sr[3]);
            atomicAdd(&part_out[b * 2 + 1], sr[4] + sr[5] + sr[6] + sr[7]);
        }
    } else if constexpr (MODE == 2) {
        // ---- h2+h3 fused: a2 tile -> LDS, partial 192->2 conv, atomics.
        short* a2loc = smem;  // staging dead after the final PIPE_BARRIER
        // acc -> a2loc rows 1..256 (row = seq - (l0-1))
        #pragma unroll
        for (int mt = 0; mt < 4; mt++)
            #pragma unroll
            for (int nt = 0; nt < 4; nt++)
                #pragma unroll
                for (int r = 0; r < 4; r++) {
                    int row = wl + mt * 16 + q * 4 + r + 1;
                    int cl = nt * 16 + lane15;
                    a2loc[(cl >> 3) * (258 * 8) + row * 8 + (cl & 7)] =
                        f2b(fmaxf(acc[mt][nt][r], 0.f));
                }
        // halo rows: wave0 -> row 0 (seq l0-1), wave1 -> row 257 (seq
        // l0+256); zero at sequence edges (matches old pre-zeroed halo).
        if (wn < 2) {
            int le = (wn == 0) ? (l0 - 1) : (l0 + 256);
            int rowdst = (wn == 0) ? 0 : 257;
            float s = 0.f;
            if (le >= 0 && le < LL) {
                int cog = co0 + lane;
                #pragma unroll 2
                for (int oc = 0; oc < 48; oc++) {
                    const short* ap = inh + ibase + (size_t)oc * RP + le * 8;
                    #pragma unroll
                    for (int tp = 0; tp < 3; tp++) {
                        bf16x8 av = *(const bf16x8*)(ap + tp * 8);
                        const short* wp =
                            wh + ((size_t)(tp * 48 + oc) * COD + cog) * 8;
                        #pragma unroll
                        for (int j = 0; j < 8; j++)
                            s += b2f(av[j]) * b2f(wp[j]);
                    }
                }
                s = fmaxf(s, 0.f);
            }
            a2loc[(lane >> 3) * (258 * 8) + rowdst * 8 + (lane & 7)] = f2b(s);
        }
        // stage w3 (fp32)
        for (int i = tid; i < 2 * 192 * 3; i += 256) ws3s[i] = w3p[i];
        __syncthreads();
        // partial h3: thread -> l = l0 + tid, both channels, 64 ci.
        int ll = tid;
        float s0 = 0.f, s1 = 0.f;
        #pragma unroll 2
        for (int cil = 0; cil < 64; cil++) {
            int cig = co0 + cil;
            const float* wp0 = ws3s + cig * 3;
            const float* wp1 = ws3s + 576 + cig * 3;
            const short* ap = a2loc + (cil >> 3) * (258 * 8) + ll * 8 +
                              (cil & 7);
            #pragma unroll
            for (int tp = 0; tp < 3; tp++) {
                float av = b2f(ap[tp * 8]);
                s0 += wp0[tp] * av;
                s1 += wp1[tp] * av;
            }
        }
        float* ob = outp + (((size_t)b * ITERS + th) * 2) * LL + l0 + ll;
        atomicAdd(ob, s0);
        atomicAdd(ob + LL, s1);
    } else {
        #pragma unroll
        for (int mt = 0; mt < 4; mt++)
            #pragma unroll
            for (int nt = 0; nt < 4; nt++)
                #pragma unroll
                for (int r = 0; r < 4; r++) {
                    int m = mt * 16 + q * 4 + r;
                    int n = co0w + nt * 16 + lane15;
                    size_t idx = obase + (size_t)(n >> 3) * RP +
                                 (l0w + m + 1) * 8 + (n & 7);
                    outh[idx] = f2b(fmaxf(acc[mt][nt][r], 0.f));
                }
    }
}

// F(t): op(t) || h1(t-1) || h2+h3(t-2). All branch reads target buffers
// written in EARLIER launches (a1 ping-pong parity breaks same-launch
// hazards). Branch offsets are multiples of 8 -> XCD key survives.
__global__ __launch_bounds__(256, 3) void fusedF(
    const short* __restrict__ ch, const short* __restrict__ cl,
    short* __restrict__ nh, short* __restrict__ nl,
    const short* __restrict__ wOph, const short* __restrict__ wH1,
    const short* __restrict__ wH2, const float* __restrict__ xf,
    const float* __restrict__ wx, const float* __restrict__ part_in,
    float* __restrict__ part_out, short* __restrict__ a1w,
    const short* __restrict__ a1r, const float* __restrict__ w3,
    float* __restrict__ out, int th, int opB, int h1B) {
    // 2 x [8 oct][130 rows] 16B-units = 33280 B (>= LSPLIT 2x[4][258] and
    // >= the 8x258x16 = 33024 B a2loc reuse). + 4.6 KB ws3 region.
    __shared__ __align__(16) short smem[2 * 8 * 130 * 8];
    __shared__ float ws3s[2 * 192 * 3];
    int bid = blockIdx.x;
    if (bid < opB) {
        conv_body<12, 48, 48, 384, 1, 0, 8>(bid, smem, ws3s, ch, cl, wOph,
                                            xf, wx, part_in, part_out, nh,
                                            nl, nullptr, nullptr, 0);
    } else if (bid < opB + h1B) {
        conv_body<12, 48, 48, 384, 0, 0, 8>(bid - opB, smem, ws3s, ch,
                                            nullptr, wH1, nullptr, nullptr,
                                            nullptr, nullptr, a1w, nullptr,
                                            nullptr, nullptr, 0);
    } else {
        conv_body<12, 48, 24, 192, 2, 1, 4>(bid - opB - h1B, smem, ws3s,
                                            a1r, nullptr, wH2, nullptr,
                                            nullptr, nullptr, nullptr,
                                            nullptr, nullptr, w3, out, th);
    }
}

extern "C" void kernel_launch(void* const* d_in, const int* in_sizes, int n_in,
                              void* d_out, int out_size, void* d_ws, size_t ws_size,
                              hipStream_t stream) {
    const float* x = (const float*)d_in[0];
    const float* proj_w = (const float*)d_in[2];
    const float* op_w = (const float*)d_in[3];
    const float* h1_w = (const float*)d_in[4];
    const float* h2_w = (const float*)d_in[5];
    const float* h3_w = (const float*)d_in[6];
    float* out = (float*)d_out;

    char* base = (char*)d_ws;
    size_t off = 0;
    auto alloc = [&](size_t bytes) {
        char* p = base + off;
        off += (bytes + 255) & ~(size_t)255;
        return p;
    };
    const size_t ITB = (size_t)BB * 48 * RP * 2;  // state buffer bytes
    short* itAh = (short*)alloc(ITB);
    short* itAl = (short*)alloc(ITB);
    short* itBh = (short*)alloc(ITB);
    short* itBl = (short*)alloc(ITB);
    short* a1A = (short*)alloc((size_t)BB * 48 * RP * 2);
    short* a1B = (short*)alloc((size_t)BB * 48 * RP * 2);
    short* wOph = (short*)alloc((size_t)3 * 48 * 384 * 8 * 2);
    short* wH1 = (short*)alloc((size_t)3 * 48 * 384 * 8 * 2);
    short* wH2 = (short*)alloc((size_t)3 * 48 * 192 * 8 * 2);
    float* wx = (float*)alloc((size_t)3 * 384 * 4);
    float* part = (float*)alloc((size_t)(ITERS + 1) * 64 * 4);
    if (off > ws_size) return;

    prep<<<6442, 256, 0, stream>>>(op_w, h1_w, h2_w, wOph, wH1, wH2, wx,
                                   itAh, itAl, itBh, itBl, a1A, a1B, part,
                                   out);
    proj_relu<<<BB * 8, 256, 0, stream>>>(x, proj_w, itAh, itAl, part);

    short* a1buf[2] = {a1A, a1B};
    short *ch = itAh, *cl = itAl, *nh = itBh, *nl = itBl;
    // Pipeline steps t=0..17: op(t<=15), h1(t-1), h2+h3(t-2) fused.
    for (int t = 0; t < ITERS + 2; t++) {
        int opB = (t < ITERS) ? 384 : 0;
        int h1B = (t >= 1 && t <= ITERS) ? 384 : 0;
        int h2B = (t >= 2 && t <= ITERS + 1) ? 192 : 0;
        int tp = (t < ITERS) ? t : 0;  // part slot (unused when opB==0)
        fusedF<<<opB + h1B + h2B, 256, 0, stream>>>(
            ch, cl, nh, nl, wOph, wH1, wH2, x, wx, part + tp * 64,
            part + (tp + 1) * 64, a1buf[(t - 1) & 1], a1buf[(t - 2) & 1],
            h3_w, out, t - 2, opB, h1B);
        if (t < ITERS) {
            short* th = ch; ch = nh; nh = th;
            short* tl = cl; cl = nl; nl = tl;
        }
    }
}

// Round 13
// 927.346 us; speedup vs baseline: 1.2088x; 1.2088x over previous
//
#include <hip/hip_runtime.h>
#include <hip/hip_bf16.h>

#define BB 32
#define WW 384
#define LL 512
#define ITERS 16
#define NPB (WW * LL)
#define LROWS 514            // 1 + 512 + 1 halo rows
#define RP (LROWS * 8)       // shorts per octet-plane (4112)

typedef __attribute__((ext_vector_type(8))) short bf16x8;
typedef __attribute__((ext_vector_type(4))) float f32x4;

__device__ __forceinline__ float b2f(short s) {
    unsigned u = ((unsigned)(unsigned short)s) << 16;
    float f;
    __builtin_memcpy(&f, &u, 4);
    return f;
}
__device__ __forceinline__ short f2b(float v) {
    __hip_bfloat16 h = __float2bfloat16(v);
    return *(short*)&h;
}

// async global->LDS, 16B per lane; LDS dest = wave-uniform base + lane*16.
__device__ __forceinline__ void gld16(const short* g, short* l) {
    __builtin_amdgcn_global_load_lds(
        (const __attribute__((address_space(1))) unsigned int*)g,
        (__attribute__((address_space(3))) unsigned int*)l, 16, 0, 0);
}

// ---------------------------------------------------------------- prep
// All one-time prep fused into ONE kernel (writes disjoint, no
// cross-reads): wsplit_op | wsplit_h1 | wsplit_h2 | wx | zero_part |
// init_rows.
__global__ __launch_bounds__(256) void prep(
    const float* __restrict__ op_w, const float* __restrict__ h1_w,
    const float* __restrict__ h2_w, short* __restrict__ wOph,
    short* __restrict__ wH1, short* __restrict__ wH2, float* __restrict__ wx,
    short* itAh, short* itAl, short* itBh, short* itBl,
    short* a1A, short* a1B, short* a2A, short* a2B, float* part) {
    int bid = blockIdx.x, tid = threadIdx.x;
    if (bid < 1728) {                      // op_w -> [3][48][384][8] bf16
        int i = bid * 256 + tid;           // 442368 = 1728*256 exact
        int e = i & 7, co = (i >> 3) % 384, oct = (i >> 3) / 384 % 48,
            tap = i / (8 * 384 * 48);
        wOph[i] = f2b(op_w[(co * 385 + oct * 8 + e) * 3 + tap]);
    } else if (bid < 3456) {               // h1_w -> [3][48][384][8]
        int i = (bid - 1728) * 256 + tid;
        int e = i & 7, co = (i >> 3) % 384, oct = (i >> 3) / 384 % 48,
            tap = i / (8 * 384 * 48);
        wH1[i] = f2b(h1_w[(co * 384 + oct * 8 + e) * 3 + tap]);
    } else if (bid < 4320) {               // h2_w -> [3][48][192][8]
        int i = (bid - 3456) * 256 + tid;  // 221184 = 864*256 exact
        int e = i & 7, co = (i >> 3) % 192, oct = (i >> 3) / 192 % 48,
            tap = i / (8 * 192 * 48);
        wH2[i] = f2b(h2_w[(co * 384 + oct * 8 + e) * 3 + tap]);
    } else if (bid < 4325) {               // wx[tap][co] fp32 x-channel
        int i = (bid - 4320) * 256 + tid;
        if (i < 3 * 384) {
            int co = i % 384, tap = i / 384;
            wx[tap * 384 + co] = op_w[(co * 385 + 384) * 3 + tap];
        }
    } else if (bid < 4330) {               // zero part
        int i = (bid - 4325) * 256 + tid;
        if (i < (ITERS + 1) * 64) part[i] = 0.f;
    } else {                               // zero halo rows (64 sub-bids)
        int rb = bid - 4330;
        int row = (rb & 1) ? (LROWS - 1) : 0;
        int b = rb >> 1;
        for (int i = tid; i < 48 * 8; i += 256) {
            size_t o = (size_t)b * 48 * RP + (size_t)(i >> 3) * RP +
                       row * 8 + (i & 7);
            itAh[o] = 0; itAl[o] = 0; itBh[o] = 0; itBl[o] = 0;
            a1A[o] = 0; a1B[o] = 0;
        }
        for (int i = tid; i < 24 * 8; i += 256) {
            size_t o = (size_t)b * 24 * RP + (size_t)(i >> 3) * RP +
                       row * 8 + (i & 7);
            a2A[o] = 0; a2B[o] = 0;
        }
    }
}

// it0 = relu(conv1d(x, proj_w)) -> octet-planar hi/lo (48 oct) + LN stats.
// bid swizzled so bid%8 == XCD key (2b + (l>>8)) & 7 (matches op readers).
__global__ __launch_bounds__(256) void proj_relu(const float* __restrict__ x,
                                                 const float* __restrict__ wp,
                                                 short* __restrict__ oh,
                                                 short* __restrict__ ol,
                                                 float* __restrict__ part) {
    int low3 = blockIdx.x & 7, r0 = blockIdx.x >> 3;   // r0 0..31
    int sl_lo = r0 & 3, chi = r0 >> 2;                 // chi 0..7
    int c3 = chi * 8 + low3;                           // 0..63
    int b = c3 >> 1, sl = ((c3 & 1) << 2) | sl_lo;
    int tid = threadIdx.x;
    __shared__ float ws[WW * 3];
    __shared__ float xs[66];
    for (int i = tid; i < WW * 3; i += 256) ws[i] = wp[i];
    int l0 = sl * 64;
    for (int i = tid; i < 66; i += 256) {
        int l = l0 + i - 1;
        xs[i] = (l >= 0 && l < LL) ? x[b * LL + l] : 0.f;
    }
    __syncthreads();
    size_t sb = (size_t)b * 48 * RP;
    float s = 0.f, sq = 0.f;
    for (int idx = tid; idx < 64 * WW; idx += 256) {
        int lo = idx / WW, co = idx % WW;
        float v = fmaxf(ws[co * 3] * xs[lo] + ws[co * 3 + 1] * xs[lo + 1] +
                            ws[co * 3 + 2] * xs[lo + 2], 0.f);
        size_t o = sb + (size_t)(co >> 3) * RP + (l0 + lo + 1) * 8 + (co & 7);
        __hip_bfloat16 h = __float2bfloat16(v);
        oh[o] = *(short*)&h;
        ol[o] = f2b(v - __bfloat162float(h));
        s += v; sq += v * v;
    }
    #pragma unroll
    for (int off = 32; off > 0; off >>= 1) {
        s += __shfl_down(s, off);
        sq += __shfl_down(sq, off);
    }
    __shared__ float sr[8];
    int w = tid >> 6;
    if ((tid & 63) == 0) { sr[w] = s; sr[4 + w] = sq; }
    __syncthreads();
    if (tid == 0) {
        atomicAdd(&part[b * 2], sr[0] + sr[1] + sr[2] + sr[3]);
        atomicAdd(&part[b * 2 + 1], sr[4] + sr[5] + sr[6] + sr[7]);
    }
}

// ------------------------------------------------- MFMA implicit-GEMM conv
// v14 == v8, the verified best (953.5us). Rounds 9-13 falsified every
// alternative: LDS-occupancy (v10: +0 at fixed grid), VGPR squeeze (v9:
// spills), cache hints (v11: nt stores bypass L2, WRITE x2), 2x grid
// (v12: -20%, smaller tiles double B traffic), h2+h3 fusion (v13: bytes
// -17% but serial halo chain + scalar-LDS h3 tail dropped the fabric
// rate 1.6 -> 1.14 TB/s, net -24%). The structure-level facts that hold:
// fusedF dur tracks L2-miss bytes at ~1.5-1.6 TB/s (fabric latency x
// outstanding-request cap at this wave count); scheduling, occupancy,
// and hints are all null levers; byte-cut fusions cost more than they
// save at this problem size. v8's composition: grouped K-chunks (GOCT=8
// for op/h1 -> 6 barriers; h2 GOCT=4 double-buffered), counted vmcnt(8)
// barrier (per wave the last STAGE DMA is followed by exactly X(4)+Y(4)
// = 8 register loads -> vmcnt(8) retires all DMAs in-order while X/Y
// cross the barrier in flight), producer-consumer XCD affinity (bid%8 ==
// (2b + (l>>8)) & 7 in every kernel), h3 folded as the 4th branch, all
// prep in one kernel. Accumulation order (kc asc, tap asc) -> absmax
// 0.002441406.

#define PIPE_BARRIER()                                                     \
    do {                                                                   \
        asm volatile("s_waitcnt vmcnt(8)" ::: "memory");                   \
        __builtin_amdgcn_sched_barrier(0);                                 \
        __builtin_amdgcn_s_barrier();                                      \
        __builtin_amdgcn_sched_barrier(0);                                 \
    } while (0)

#define MMAC(A, B, MT, NT)                                                 \
    acc[MT][NT] = __builtin_amdgcn_mfma_f32_16x16x32_bf16(A, B,            \
                                                          acc[MT][NT], 0, 0, 0);

// Stage spans [S0,S1) of group KG into buffer TB. Span s_ = 64 16B-units,
// handled by wave (s_ - S0) % 4; last span clamped (benign same-data
// overlap). LDS layout per buffer: [GOCT][TLROWS] 16B-units.
#define STAGE_R(KG, TB, S0, S1)                                            \
    do {                                                                   \
        short* sb_ = smem + (TB) * ASZ;                                    \
        _Pragma("unroll")                                                  \
        for (int r_ = 0; r_ < ((S1) - (S0) + 3) / 4; r_++) {               \
            int s_ = (S0) + r_ * 4 + wn;                                   \
            if (s_ < (S1)) {                                               \
                int u0_ = s_ * 64;                                         \
                if (u0_ > AU - 64) u0_ = AU - 64;                          \
                int u_ = u0_ + lane;                                       \
                int oc_ = u_ / TLROWS;                                     \
                int rw_ = u_ - oc_ * TLROWS;                               \
                gld16(inh + ibase + (size_t)((KG) * GOCT + oc_) * RP +     \
                          (size_t)(l0 + rw_) * 8,                          \
                      sb_ + u0_ * 8);                                      \
            }                                                              \
        }                                                                  \
    } while (0)

#define DECL_B(S) bf16x8 fb0##S, fb1##S, fb2##S, fb3##S;

// Prefetch B frags for (tap T, sub-chunk KC) into set S (global->VGPR).
#define LOADB(S, T, KC)                                                    \
    do {                                                                   \
        const short* bp_ = wh + ((((size_t)(T) * CHUNKS + (KC)) * 4 + q) * \
                                     COD + co0w + lane15) * 8;             \
        fb0##S = *(const bf16x8*)(bp_);                                    \
        fb1##S = *(const bf16x8*)(bp_ + 16 * 8);                           \
        fb2##S = *(const bf16x8*)(bp_ + 32 * 8);                           \
        fb3##S = *(const bf16x8*)(bp_ + 48 * 8);                           \
    } while (0)

// One tap-step: 4 ds_read_b128 (A, sub-chunk OG of the group) + 16 MFMA.
#define COMP_TAP(SB, OG, T, S)                                             \
    do {                                                                   \
        const short* As_ = (SB);                                           \
        int ar_ = ((OG) * 4 + q) * TLROWS + wl + lane15 + (T);             \
        bf16x8 fa0 = *(const bf16x8*)(As_ + ar_ * 8);                      \
        bf16x8 fa1 = *(const bf16x8*)(As_ + (ar_ + 16) * 8);               \
        bf16x8 fa2 = *(const bf16x8*)(As_ + (ar_ + 32) * 8);               \
        bf16x8 fa3 = *(const bf16x8*)(As_ + (ar_ + 48) * 8);               \
        MMAC(fa0, fb0##S, 0, 0) MMAC(fa0, fb1##S, 0, 1)                    \
        MMAC(fa0, fb2##S, 0, 2) MMAC(fa0, fb3##S, 0, 3)                    \
        MMAC(fa1, fb0##S, 1, 0) MMAC(fa1, fb1##S, 1, 1)                    \
        MMAC(fa1, fb2##S, 1, 2) MMAC(fa1, fb3##S, 1, 3)                    \
        MMAC(fa2, fb0##S, 2, 0) MMAC(fa2, fb1##S, 2, 1)                    \
        MMAC(fa2, fb2##S, 2, 2) MMAC(fa2, fb3##S, 2, 3)                    \
        MMAC(fa3, fb0##S, 3, 0) MMAC(fa3, fb1##S, 3, 1)                    \
        MMAC(fa3, fb2##S, 3, 2) MMAC(fa3, fb3##S, 3, 3)                    \
    } while (0)

template <int CHUNKS, int IOCT, int OOCT, int COD, int MODE, int LSPLIT,
          int GOCT>
__device__ __forceinline__ void conv_body(
    int bid, short* smem,
    const short* __restrict__ inh, const short* __restrict__ inl,
    const short* __restrict__ wh, const float* __restrict__ xf,
    const float* __restrict__ wx, const float* __restrict__ part_in,
    float* __restrict__ part_out, short* __restrict__ outh,
    short* __restrict__ outl) {
    constexpr int TLROWS = LSPLIT ? 258 : 130;  // staged halo rows per octet
    constexpr int SUBS = GOCT / 4;              // sub-chunks per group
    constexpr int NG = CHUNKS / SUBS;           // groups (= barriers)
    constexpr int ASZ = GOCT * TLROWS * 8;      // shorts per A buffer
    constexpr int AU = GOCT * TLROWS;           // A 16B-units per group
    constexpr int ANS = (AU + 63) / 64;         // spans per group
    constexpr int SPS = (ANS + SUBS - 1) / SUBS;  // spans per sub-chunk

    int tid = threadIdx.x;
    int lane = tid & 63;
    int wn = __builtin_amdgcn_readfirstlane(tid >> 6);
    int lane15 = lane & 15, q = lane >> 4;
    int b, l0, co0, wl, wco;
    if (LSPLIT) {
        // XCD-keyed decode: bid%8 == (2b + lt2) & 7, lt2 = l>>8.
        int low3 = bid & 7, r0 = bid >> 3;      // r0 0..23
        int ct = r0 % 3, chi = r0 / 3;          // chi 0..7
        int c2 = chi * 8 + low3;                // 0..63
        b = c2 >> 1; l0 = (c2 & 1) * 256; co0 = ct * 64;
        wl = wn * 64; wco = 0;
    } else {
        // XCD-keyed decode: bid%8 == (2b + (lt>>1)) & 7, lt = l>>7 (0..3).
        int low3 = bid & 7, r0 = bid >> 3;      // r0 0..47
        int ct = r0 % 3, s2 = r0 / 3;           // s2 0..15
        int ltlo = s2 & 1, chi = s2 >> 1;       // chi 0..7
        int c = chi * 8 + low3;                 // 0..63
        b = c >> 1;
        int lt = ((c & 1) << 1) | ltlo;         // 0..3
        l0 = lt * 128; co0 = ct * 128;
        wl = (wn >> 1) * 64; wco = (wn & 1) * 64;
    }
    const int co0w = co0 + wco;
    const size_t ibase = (size_t)b * IOCT * RP;

    f32x4 acc[4][4];
    #pragma unroll
    for (int i = 0; i < 4; i++)
        #pragma unroll
        for (int j = 0; j < 4; j++) acc[i][j] = (f32x4){0.f, 0.f, 0.f, 0.f};

    DECL_B(X)
    DECL_B(Y)
    DECL_B(Z)
    STAGE_R(0, 0, 0, ANS);
    LOADB(X, 0, 0);
    LOADB(Y, 1, 0);
    PIPE_BARRIER();    // vmcnt(8): STAGE(0) landed, X/Y stay in flight
    #pragma unroll 2
    for (int g = 0; g < NG; g++) {
        int cur = g & 1;
        short* sb = smem + cur * ASZ;
        #pragma unroll
        for (int s = 0; s < SUBS; s++) {
            int kc = g * SUBS + s;
            LOADB(Z, 2, kc);
            if (g + 1 < NG) {
                int s0 = s * SPS;
                int s1 = (s0 + SPS > ANS) ? ANS : s0 + SPS;
                STAGE_R(g + 1, cur ^ 1, s0, s1);
            }
            COMP_TAP(sb, s, 0, X);
            if (kc + 1 < CHUNKS) LOADB(X, 0, kc + 1);
            COMP_TAP(sb, s, 1, Y);
            if (kc + 1 < CHUNKS) LOADB(Y, 1, kc + 1);
            COMP_TAP(sb, s, 2, Z);
        }
        PIPE_BARRIER();  // vmcnt(8): STAGE(g+1) landed; X/Y cross over
    }

    int l0w = l0 + wl;
    const size_t obase = (size_t)b * OOCT * RP;
    if constexpr (MODE == 1) {
        float s_in = part_in[b * 2], sq_in = part_in[b * 2 + 1];
        float mu = s_in / (float)NPB;
        float var = sq_in / (float)NPB - mu * mu;
        float rs = rsqrtf(var + 1e-5f);
        const float* xb = xf + b * LL;
        float s = 0.f, sq = 0.f;
        #pragma unroll
        for (int nt = 0; nt < 4; nt++) {
            int n = co0w + nt * 16 + lane15;
            float w0 = wx[n], w1 = wx[384 + n], w2 = wx[768 + n];
            #pragma unroll
            for (int mt = 0; mt < 4; mt++)
                #pragma unroll
                for (int r = 0; r < 4; r++) {
                    int m = mt * 16 + q * 4 + r;
                    int l = l0w + m;
                    size_t idx = ibase + (size_t)(n >> 3) * RP +
                                 (l + 1) * 8 + (n & 7);
                    // x-channel contribution (fp32-exact)
                    float xm1 = (l > 0) ? xb[l - 1] : 0.f;
                    float xp1 = (l < LL - 1) ? xb[l + 1] : 0.f;
                    float c = acc[mt][nt][r] + w0 * xm1 + w1 * xb[l] + w2 * xp1;
                    float itv = b2f(inh[idx]) + b2f(inl[idx]);
                    float xl = (itv - mu) * rs;
                    float nv = xl - 0.1f * c - 0.2f * fmaxf(xl, 0.f);
                    s += nv;
                    sq += nv * nv;
                    __hip_bfloat16 h = __float2bfloat16(nv);
                    outh[idx] = *(short*)&h;
                    outl[idx] = f2b(nv - __bfloat162float(h));
                }
        }
        #pragma unroll
        for (int off = 32; off > 0; off >>= 1) {
            s += __shfl_down(s, off);
            sq += __shfl_down(sq, off);
        }
        __shared__ float sr[8];
        if (lane == 0) { sr[wn] = s; sr[4 + wn] = sq; }
        __syncthreads();
        if (tid == 0) {
            atomicAdd(&part_out[b * 2], sr[0] + sr[1] + sr[2] + sr[3]);
            atomicAdd(&part_out[b * 2 + 1], sr[4] + sr[5] + sr[6] + sr[7]);
        }
    } else {
        #pragma unroll
        for (int mt = 0; mt < 4; mt++)
            #pragma unroll
            for (int nt = 0; nt < 4; nt++)
                #pragma unroll
                for (int r = 0; r < 4; r++) {
                    int m = mt * 16 + q * 4 + r;
                    int n = co0w + nt * 16 + lane15;
                    size_t idx = obase + (size_t)(n >> 3) * RP +
                                 (l0w + m + 1) * 8 + (n & 7);
                    outh[idx] = f2b(fmaxf(acc[mt][nt][r], 0.f));
                }
    }
}

// Final 192->2 conv from a2 [32][24oct][514][8] bf16 octet-planar, folded
// into fusedF as the 4th branch (256 threads: 128 l-values x 2 channels).
// bid%8 == (2b + (l>>8)) & 7 matches the h2 writers of a2.
__device__ __forceinline__ void h3_body(int bid, short* smem,
                                        const short* __restrict__ a2,
                                        const float* __restrict__ w3,
                                        float* __restrict__ out, int t) {
    float* ws3 = (float*)smem;  // 2*192*3 floats = 4.6 KB
    int tid = threadIdx.x;
    for (int i = tid; i < 2 * 192 * 3; i += 256) ws3[i] = w3[i];
    __syncthreads();
    int low3 = bid & 7, r0 = bid >> 3;   // r0 0..15
    int qlo = r0 & 1, chi = r0 >> 1;     // chi 0..7
    int c = chi * 8 + low3;              // 0..63
    int b = c >> 1;
    int qq = ((c & 1) << 1) | qlo;       // l quarter 0..3
    int l = qq * 128 + (tid >> 1);
    int ch = tid & 1;
    const short* ab = a2 + (size_t)b * 24 * RP;
    const float* wc = ws3 + ch * 576;
    float a = 0.f;
    #pragma unroll 4
    for (int oct = 0; oct < 24; oct++) {
        const short* p = ab + (size_t)oct * RP + l * 8;  // row l = seq l-1
        bf16x8 v0 = *(const bf16x8*)p;
        bf16x8 v1 = *(const bf16x8*)(p + 8);
        bf16x8 v2 = *(const bf16x8*)(p + 16);
        #pragma unroll
        for (int j = 0; j < 8; j++) {
            const float* wp = wc + (oct * 8 + j) * 3;
            a += wp[0] * b2f(v0[j]) + wp[1] * b2f(v1[j]) + wp[2] * b2f(v2[j]);
        }
    }
    out[(((size_t)b * ITERS + t) * 2 + ch) * LL + l] = a;
}

// F(t): op(t) || h1(t-1) || h2(t-2) || h3(t-3). All branch reads target
// buffers written in EARLIER launches (a1/a2 ping-pong parities break
// same-launch hazards; h3 reads a2 parity (t+1)&1, h2 writes t&1).
// Branch offsets are multiples of 8 -> the XCD key survives the split.
__global__ __launch_bounds__(256, 3) void fusedF(
    const short* __restrict__ ch, const short* __restrict__ cl,
    short* __restrict__ nh, short* __restrict__ nl,
    const short* __restrict__ wOph, const short* __restrict__ wH1,
    const short* __restrict__ wH2, const float* __restrict__ xf,
    const float* __restrict__ wx, const float* __restrict__ part_in,
    float* __restrict__ part_out, short* __restrict__ a1w,
    const short* __restrict__ a1r, short* __restrict__ a2w,
    const short* __restrict__ a2r, const float* __restrict__ w3,
    float* __restrict__ out, int th3, int opB, int h1B, int h2B) {
    // 2 x [8 oct][130 rows] 16B-units = 33280 B (>= LSPLIT's 2x[4][258]).
    __shared__ __align__(16) short smem[2 * 8 * 130 * 8];
    int bid = blockIdx.x;
    if (bid < opB) {
        conv_body<12, 48, 48, 384, 1, 0, 8>(bid, smem, ch, cl, wOph, xf, wx,
                                            part_in, part_out, nh, nl);
    } else if (bid < opB + h1B) {
        conv_body<12, 48, 48, 384, 0, 0, 8>(bid - opB, smem, ch, nullptr,
                                            wH1, nullptr, nullptr, nullptr,
                                            nullptr, a1w, nullptr);
    } else if (bid < opB + h1B + h2B) {
        conv_body<12, 48, 24, 192, 0, 1, 4>(bid - opB - h1B, smem, a1r,
                                            nullptr, wH2, nullptr, nullptr,
                                            nullptr, nullptr, a2w, nullptr);
    } else {
        h3_body(bid - opB - h1B - h2B, smem, a2r, w3, out, th3);
    }
}

extern "C" void kernel_launch(void* const* d_in, const int* in_sizes, int n_in,
                              void* d_out, int out_size, void* d_ws, size_t ws_size,
                              hipStream_t stream) {
    const float* x = (const float*)d_in[0];
    const float* proj_w = (const float*)d_in[2];
    const float* op_w = (const float*)d_in[3];
    const float* h1_w = (const float*)d_in[4];
    const float* h2_w = (const float*)d_in[5];
    const float* h3_w = (const float*)d_in[6];
    float* out = (float*)d_out;

    char* base = (char*)d_ws;
    size_t off = 0;
    auto alloc = [&](size_t bytes) {
        char* p = base + off;
        off += (bytes + 255) & ~(size_t)255;
        return p;
    };
    const size_t ITB = (size_t)BB * 48 * RP * 2;  // state buffer bytes
    short* itAh = (short*)alloc(ITB);
    short* itAl = (short*)alloc(ITB);
    short* itBh = (short*)alloc(ITB);
    short* itBl = (short*)alloc(ITB);
    short* a1A = (short*)alloc((size_t)BB * 48 * RP * 2);
    short* a1B = (short*)alloc((size_t)BB * 48 * RP * 2);
    short* a2A = (short*)alloc((size_t)BB * 24 * RP * 2);
    short* a2B = (short*)alloc((size_t)BB * 24 * RP * 2);
    short* wOph = (short*)alloc((size_t)3 * 48 * 384 * 8 * 2);
    short* wH1 = (short*)alloc((size_t)3 * 48 * 384 * 8 * 2);
    short* wH2 = (short*)alloc((size_t)3 * 48 * 192 * 8 * 2);
    float* wx = (float*)alloc((size_t)3 * 384 * 4);
    float* part = (float*)alloc((size_t)(ITERS + 1) * 64 * 4);
    if (off > ws_size) return;

    prep<<<4394, 256, 0, stream>>>(op_w, h1_w, h2_w, wOph, wH1, wH2, wx,
                                   itAh, itAl, itBh, itBl, a1A, a1B, a2A,
                                   a2B, part);
    proj_relu<<<BB * 8, 256, 0, stream>>>(x, proj_w, itAh, itAl, part);

    short* a1buf[2] = {a1A, a1B};
    short* a2buf[2] = {a2A, a2B};
    short *ch = itAh, *cl = itAl, *nh = itBh, *nl = itBl;
    // Pipeline steps t=0..18: op(t<=15), h1(t-1), h2(t-2), h3(t-3) fused.
    for (int t = 0; t < ITERS + 3; t++) {
        int opB = (t < ITERS) ? 384 : 0;
        int h1B = (t >= 1 && t <= ITERS) ? 384 : 0;
        int h2B = (t >= 2 && t <= ITERS + 1) ? 192 : 0;
        int h3B = (t >= 3 && t <= ITERS + 2) ? 128 : 0;
        int tp = (t < ITERS) ? t : 0;  // part slot (unused when opB==0)
        fusedF<<<opB + h1B + h2B + h3B, 256, 0, stream>>>(
            ch, cl, nh, nl, wOph, wH1, wH2, x, wx, part + tp * 64,
            part + (tp + 1) * 64, a1buf[(t - 1) & 1], a1buf[(t - 2) & 1],
            a2buf[(t - 2) & 1], a2buf[(t + 1) & 1], h3_w, out, t - 3,
            opB, h1B, h2B);
        if (t < ITERS) {
            short* th = ch; ch = nh; nh = th;
            short* tl = cl; cl = nl; nl = tl;
        }
    }
}